// Round 7
// baseline (1574.151 us; speedup 1.0000x reference)
//
#include <hip/hip_runtime.h>
#include <hip/hip_bf16.h>
#include <math.h>

// N=50000, E=800000, D_IN=256, D_E=64, H1=H2=128, N_OUT=64
typedef unsigned short u16;
typedef unsigned int u32;
typedef __attribute__((ext_vector_type(8))) short bf16x8;
typedef __attribute__((ext_vector_type(4))) float f32x4;

__device__ inline u16 f2bf(float x) {
    unsigned u = __float_as_uint(x);
    unsigned r = u + 0x7fff + ((u >> 16) & 1);
    return (u16)(r >> 16);
}
__device__ inline float bf2f(u16 h) { return __uint_as_float(((unsigned)h) << 16); }
__device__ inline void bsplit(float x, u16& h, u16& l) {
    h = f2bf(x);
    float r = x - bf2f(h);
    l = f2bf(r);
}

// ---------------------------------------------------------------------------
// CSR build
// ---------------------------------------------------------------------------
__global__ void count_deg(const int* __restrict__ dst, int* __restrict__ cnt, int E) {
    int e = blockIdx.x * blockDim.x + threadIdx.x;
    if (e < E) atomicAdd(&cnt[dst[e]], 1);
}

__global__ __launch_bounds__(1024) void scan_a(const int* __restrict__ cnt,
                                               int* __restrict__ out,
                                               int* __restrict__ partials, int N) {
    __shared__ int sh[1024];
    int tid = threadIdx.x;
    int gid = blockIdx.x * 1024 + tid;
    int v = (gid < N) ? cnt[gid] : 0;
    sh[tid] = v;
    for (int off = 1; off < 1024; off <<= 1) {
        __syncthreads();
        int add = (tid >= off) ? sh[tid - off] : 0;
        __syncthreads();
        sh[tid] += add;
    }
    __syncthreads();
    if (gid <= N) out[gid] = sh[tid] - v;
    if (tid == 1023) partials[blockIdx.x] = sh[1023];
}

__global__ void scan_b(int* __restrict__ partials, int nb) {
    if (threadIdx.x == 0 && blockIdx.x == 0) {
        int run = 0;
        for (int i = 0; i < nb; ++i) { int t = partials[i]; partials[i] = run; run += t; }
    }
}

__global__ __launch_bounds__(1024) void scan_c(int* __restrict__ out,
                                               const int* __restrict__ partials,
                                               int* __restrict__ fillb, int N) {
    int gid = blockIdx.x * 1024 + threadIdx.x;
    if (gid <= N) {
        int v = out[gid] + partials[blockIdx.x];
        out[gid] = v;
        fillb[gid] = v;
    }
}

__global__ void fill_edges(const int* __restrict__ src, const int* __restrict__ dst,
                           int* __restrict__ fillb, int2* __restrict__ esi, int E) {
    int e = blockIdx.x * blockDim.x + threadIdx.x;
    if (e < E) {
        int d = dst[e];
        int slot = atomicAdd(&fillb[d], 1);
        esi[slot] = make_int2(src[e], e);
    }
}

// ---------------------------------------------------------------------------
// prep_weights: one kernel for all weight prep.
// blocks 0..575      : layer-1 Wcat row r (K=256) -> Wc1H/L + bcat1
// blocks 576..1151   : layer-2 Wcat row r (K=128) -> Wc2H/L + bcat2
// block 1152 / 1153  : WeT1 / WeT2 (64x128 transpose)
// block 1154         : Wm split (64x256)
// Wcat rows: [Wq; Wk; Wv; Wskip; WqWe-comb(64 rows)]
// ---------------------------------------------------------------------------
__global__ __launch_bounds__(256) void prep_weights(
    const float* __restrict__ Wq1, const float* __restrict__ Wk1,
    const float* __restrict__ Wv1, const float* __restrict__ Ws1,
    const float* __restrict__ We1,
    const float* __restrict__ bq1, const float* __restrict__ bk1,
    const float* __restrict__ bv1, const float* __restrict__ bs1,
    const float* __restrict__ Wq2, const float* __restrict__ Wk2,
    const float* __restrict__ Wv2, const float* __restrict__ Ws2,
    const float* __restrict__ We2,
    const float* __restrict__ bq2, const float* __restrict__ bk2,
    const float* __restrict__ bv2, const float* __restrict__ bs2,
    const float* __restrict__ Wm,
    u16* __restrict__ Wc1H, u16* __restrict__ Wc1L,
    u16* __restrict__ Wc2H, u16* __restrict__ Wc2L,
    float* __restrict__ bcat1, float* __restrict__ bcat2,
    float* __restrict__ WeT1, float* __restrict__ WeT2,
    u16* __restrict__ WmH, u16* __restrict__ WmL) {
    int b = blockIdx.x;
    int t = threadIdx.x;
    if (b < 1152) {
        int L = b / 576;
        int r = b - L * 576;
        int K = L ? 128 : 256;
        const float* Wq = L ? Wq2 : Wq1;
        const float* We = L ? We2 : We1;
        u16* WH = L ? Wc2H : Wc1H;
        u16* WL = L ? Wc2L : Wc1L;
        float* bcat = L ? bcat2 : bcat1;
        float val = 0.f;
        bool have = t < K;
        if (r < 512) {
            int sub = r >> 7, rr = r & 127;
            const float* Wsrc = L ? (sub == 0 ? Wq2 : sub == 1 ? Wk2 : sub == 2 ? Wv2 : Ws2)
                                  : (sub == 0 ? Wq1 : sub == 1 ? Wk1 : sub == 2 ? Wv1 : Ws1);
            if (have) val = Wsrc[(size_t)rr * K + t];
            if (t == 0) {
                const float* bsrc = L ? (sub == 0 ? bq2 : sub == 1 ? bk2 : sub == 2 ? bv2 : bs2)
                                      : (sub == 0 ? bq1 : sub == 1 ? bk1 : sub == 2 ? bv1 : bs1);
                bcat[r] = bsrc[rr];
            }
        } else {
            int o = r - 512;
            if (have) {
                float s = 0.f;
                for (int h = 0; h < 128; ++h)
                    s = fmaf(We[h * 64 + o], Wq[(size_t)h * K + t], s);
                val = s;
            }
            if (t == 0) {
                const float* bq = L ? bq2 : bq1;
                float sb = 0.f;
                for (int h = 0; h < 128; ++h) sb = fmaf(We[h * 64 + o], bq[h], sb);
                bcat[r] = sb;
            }
        }
        if (have) {
            u16 h, l;
            bsplit(val, h, l);
            WH[(size_t)r * K + t] = h;
            WL[(size_t)r * K + t] = l;
        }
    } else if (b == 1152 || b == 1153) {
        const float* We = (b == 1152) ? We1 : We2;
        float* WeT = (b == 1152) ? WeT1 : WeT2;
        for (int i = t; i < 128 * 64; i += 256)
            WeT[(i & 63) * 128 + (i >> 6)] = We[i];
    } else {
        for (int i = t; i < 64 * 256; i += 256) {
            u16 h, l;
            bsplit(Wm[i], h, l);
            WmH[i] = h;
            WmL[i] = l;
        }
    }
}

// ---------------------------------------------------------------------------
// split fp32 array into bf16 hi/lo planes
// ---------------------------------------------------------------------------
__global__ void split_planes(const float* __restrict__ src, u16* __restrict__ hi,
                             u16* __restrict__ lo, int n4) {
    int i = (blockIdx.x * blockDim.x + threadIdx.x) * 4;
    if (i < n4) {
        float4 v = *reinterpret_cast<const float4*>(&src[i]);
        u16 h0, h1, h2, h3, l0, l1, l2, l3;
        bsplit(v.x, h0, l0); bsplit(v.y, h1, l1);
        bsplit(v.z, h2, l2); bsplit(v.w, h3, l3);
        *reinterpret_cast<ushort4*>(&hi[i]) = make_ushort4(h0, h1, h2, h3);
        *reinterpret_cast<ushort4*>(&lo[i]) = make_ushort4(l0, l1, l2, l3);
    }
}

// ---------------------------------------------------------------------------
// Split-bf16 MFMA GEMM (as R5): Out[n][o] = bias[o] + sum_k X[n][k]*W[o][k]
// ---------------------------------------------------------------------------
#define BM 128
#define BO 64
#define BKX 64
#define LSTR 72
__global__ __launch_bounds__(256) void gemm_mfma(
    const u16* __restrict__ XH, const u16* __restrict__ XL, int ldx,
    const u16* __restrict__ WH, const u16* __restrict__ WL,
    const float* __restrict__ bias, float* __restrict__ Out, int ldo,
    int Nrows, int K) {
    __shared__ __align__(16) u16 XsH[BM * LSTR];
    __shared__ __align__(16) u16 XsL[BM * LSTR];
    __shared__ __align__(16) u16 WsH[BO * LSTR];
    __shared__ __align__(16) u16 WsL[BO * LSTR];
    int n0 = blockIdx.x * BM, o0 = blockIdx.y * BO;
    int t = threadIdx.x, wid = t >> 6, lane = t & 63;
    int xr = t >> 1, xk = (t & 1) * 32;
    int wr = t >> 2, wk = (t & 3) * 16;
    bool xok = (n0 + xr) < Nrows;
    const u16* xh = XH + (size_t)(n0 + xr) * ldx + xk;
    const u16* xl = XL + (size_t)(n0 + xr) * ldx + xk;
    const u16* wh = WH + (size_t)(o0 + wr) * K + wk;
    const u16* wl = WL + (size_t)(o0 + wr) * K + wk;
    f32x4 acc[2][4] = {};
    for (int k0 = 0; k0 < K; k0 += BKX) {
#pragma unroll
        for (int j = 0; j < 4; ++j) {
            bf16x8 vh = {0, 0, 0, 0, 0, 0, 0, 0};
            bf16x8 vl = {0, 0, 0, 0, 0, 0, 0, 0};
            if (xok) {
                vh = *reinterpret_cast<const bf16x8*>(xh + k0 + 8 * j);
                vl = *reinterpret_cast<const bf16x8*>(xl + k0 + 8 * j);
            }
            *reinterpret_cast<bf16x8*>(&XsH[xr * LSTR + xk + 8 * j]) = vh;
            *reinterpret_cast<bf16x8*>(&XsL[xr * LSTR + xk + 8 * j]) = vl;
        }
#pragma unroll
        for (int j = 0; j < 2; ++j) {
            *reinterpret_cast<bf16x8*>(&WsH[wr * LSTR + wk + 8 * j]) =
                *reinterpret_cast<const bf16x8*>(wh + k0 + 8 * j);
            *reinterpret_cast<bf16x8*>(&WsL[wr * LSTR + wk + 8 * j]) =
                *reinterpret_cast<const bf16x8*>(wl + k0 + 8 * j);
        }
        __syncthreads();
#pragma unroll
        for (int kc = 0; kc < 2; ++kc) {
            int kf = kc * 32 + (lane >> 4) * 8;
            int ar = wid * 32 + (lane & 15);
            bf16x8 aH0 = *reinterpret_cast<const bf16x8*>(&XsH[ar * LSTR + kf]);
            bf16x8 aH1 = *reinterpret_cast<const bf16x8*>(&XsH[(ar + 16) * LSTR + kf]);
            bf16x8 aL0 = *reinterpret_cast<const bf16x8*>(&XsL[ar * LSTR + kf]);
            bf16x8 aL1 = *reinterpret_cast<const bf16x8*>(&XsL[(ar + 16) * LSTR + kf]);
#pragma unroll
            for (int c = 0; c < 4; ++c) {
                int br = c * 16 + (lane & 15);
                bf16x8 bH = *reinterpret_cast<const bf16x8*>(&WsH[br * LSTR + kf]);
                bf16x8 bL = *reinterpret_cast<const bf16x8*>(&WsL[br * LSTR + kf]);
                acc[0][c] = __builtin_amdgcn_mfma_f32_16x16x32_bf16(aH0, bH, acc[0][c], 0, 0, 0);
                acc[1][c] = __builtin_amdgcn_mfma_f32_16x16x32_bf16(aH1, bH, acc[1][c], 0, 0, 0);
                acc[0][c] = __builtin_amdgcn_mfma_f32_16x16x32_bf16(aH0, bL, acc[0][c], 0, 0, 0);
                acc[1][c] = __builtin_amdgcn_mfma_f32_16x16x32_bf16(aH1, bL, acc[1][c], 0, 0, 0);
                acc[0][c] = __builtin_amdgcn_mfma_f32_16x16x32_bf16(aL0, bH, acc[0][c], 0, 0, 0);
                acc[1][c] = __builtin_amdgcn_mfma_f32_16x16x32_bf16(aL1, bH, acc[1][c], 0, 0, 0);
            }
        }
        __syncthreads();
    }
#pragma unroll
    for (int c = 0; c < 4; ++c) {
        int col = o0 + c * 16 + (lane & 15);
        float bb = bias ? bias[col] : 0.f;
#pragma unroll
        for (int r = 0; r < 2; ++r) {
            int rb = n0 + wid * 32 + r * 16 + (lane >> 4) * 4;
#pragma unroll
            for (int q = 0; q < 4; ++q) {
                int row = rb + q;
                if (row < Nrows) Out[(size_t)row * ldo + col] = acc[r][c][q] + bb;
            }
        }
    }
}

// ---------------------------------------------------------------------------
// pack_attn: in-place repack of QKVS rows.
// K section (floats 128..255): k-pairs (k[j], k[j+64]) -> float2 at 128+2j
// V section (floats 256..383): bf16 pairs packed into u32 at float idx 256+j
// One wave per row; reads complete into regs before stores (same wave).
// ---------------------------------------------------------------------------
__global__ __launch_bounds__(256) void pack_attn(float* __restrict__ QKVS, int Nn) {
    int gwid = (blockIdx.x * blockDim.x + threadIdx.x) >> 6;
    int lane = threadIdx.x & 63;
    int nw = (gridDim.x * blockDim.x) >> 6;
    for (int n = gwid; n < Nn; n += nw) {
        float* row = QKVS + (size_t)n * 576;
        float k0 = row[128 + lane], k1 = row[192 + lane];
        float v0 = row[256 + lane], v1 = row[320 + lane];
        u32 vp = ((u32)f2bf(v1) << 16) | (u32)f2bf(v0);
        *reinterpret_cast<float2*>(&row[128 + 2 * lane]) = make_float2(k0, k1);
        reinterpret_cast<u32*>(row)[256 + lane] = vp;
    }
}

// ---------------------------------------------------------------------------
// attn4: fused attention + epilogue. Wave per node, 12-edge batches.
// Reads packed K (float2), packed V (bf16 u32), fp32 Ae. exp2-domain softmax.
// Epilogue: out = av + We*aa ; beta gate ; leaky relu ; write hi/lo planes.
// ---------------------------------------------------------------------------
#define AB 12
__global__ __launch_bounds__(256) void attn4(
    const int* __restrict__ row_ptr, const int2* __restrict__ esi,
    const float* __restrict__ QKVS, const float* __restrict__ Ae,
    const float* __restrict__ WeT, const float* __restrict__ Wbeta,
    u16* __restrict__ XoH, u16* __restrict__ XoL, int coff, int Nn) {
    __shared__ float WeS[64 * 128];
    __shared__ float wbA[128], wbB[128];
    int t = threadIdx.x;
    for (int i = t; i < 64 * 128; i += 256) WeS[i] = WeT[i];
    if (t < 128) {
        float w3 = Wbeta[256 + t];
        wbA[t] = Wbeta[t] + w3;
        wbB[t] = Wbeta[128 + t] - w3;
    }
    __syncthreads();
    int wid = t >> 6, lane = t & 63;
    const float RS2 = 0.088388347648318447f * 1.4426950408889634f; // 1/sqrt(128)*log2e
    for (int n = blockIdx.x * 4 + wid; n < Nn; n += gridDim.x * 4) {
        int r0 = row_ptr[n], r1 = row_ptr[n + 1];
        const float* qrow = QKVS + (size_t)n * 576;
        float q0  = qrow[lane];
        float q1  = qrow[64 + lane];
        float qe0 = qrow[512 + lane];
        float m = -1e30f, l = 0.f, av0 = 0.f, av1 = 0.f, aa = 0.f;
        for (int p = r0; p < r1; p += AB) {
            int2 se[AB];
#pragma unroll
            for (int i = 0; i < AB; ++i) {
                int pp = (p + i < r1) ? p + i : r1 - 1;
                se[i] = esi[pp];
            }
            float2 kp[AB];
            u32 vu[AB];
            float af[AB];
#pragma unroll
            for (int i = 0; i < AB; ++i)
                kp[i] = *reinterpret_cast<const float2*>(
                    &QKVS[(size_t)se[i].x * 576 + 128 + 2 * lane]);
#pragma unroll
            for (int i = 0; i < AB; ++i)
                vu[i] = reinterpret_cast<const u32*>(
                    QKVS + (size_t)se[i].x * 576)[256 + lane];
#pragma unroll
            for (int i = 0; i < AB; ++i) af[i] = Ae[(size_t)se[i].y * 64 + lane];
            float d[AB];
#pragma unroll
            for (int i = 0; i < AB; ++i)
                d[i] = fmaf(q0, kp[i].x, fmaf(q1, kp[i].y, qe0 * af[i]));
#pragma unroll
            for (int off = 32; off; off >>= 1) {
#pragma unroll
                for (int i = 0; i < AB; ++i) d[i] += __shfl_xor(d[i], off, 64);
            }
            float sc[AB];
#pragma unroll
            for (int i = 0; i < AB; ++i) sc[i] = (p + i < r1) ? d[i] * RS2 : -1e30f;
            float bm = sc[0];
#pragma unroll
            for (int i = 1; i < AB; ++i) bm = fmaxf(bm, sc[i]);
            float mn = fmaxf(m, bm);
            float scale = exp2f(m - mn);
            float w[AB];
#pragma unroll
            for (int i = 0; i < AB; ++i) w[i] = exp2f(sc[i] - mn);
            float ws = 0.f;
#pragma unroll
            for (int i = 0; i < AB; ++i) ws += w[i];
            l = fmaf(l, scale, ws);
            float s_aa = 0.f, s0 = 0.f, s1 = 0.f;
#pragma unroll
            for (int i = 0; i < AB; ++i) {
                float v0 = __uint_as_float(vu[i] << 16);
                float v1 = __uint_as_float(vu[i] & 0xffff0000u);
                s_aa = fmaf(w[i], af[i], s_aa);
                s0   = fmaf(w[i], v0, s0);
                s1   = fmaf(w[i], v1, s1);
            }
            aa  = fmaf(aa,  scale, s_aa);
            av0 = fmaf(av0, scale, s0);
            av1 = fmaf(av1, scale, s1);
            m = mn;
        }
        float inv = 1.0f / (l + 1e-16f);
        av0 *= inv; av1 *= inv; aa *= inv;
        float out0 = av0, out1 = av1;
#pragma unroll
        for (int j = 0; j < 64; ++j) {
            float aj = __shfl(aa, j, 64);
            out0 = fmaf(aj, WeS[j * 128 + lane], out0);
            out1 = fmaf(aj, WeS[j * 128 + 64 + lane], out1);
        }
        float xr0 = qrow[384 + lane], xr1 = qrow[448 + lane];
        float bp = wbA[lane] * out0 + wbA[64 + lane] * out1 +
                   wbB[lane] * xr0  + wbB[64 + lane] * xr1;
#pragma unroll
        for (int off = 32; off; off >>= 1) bp += __shfl_xor(bp, off, 64);
        float beta = 1.0f / (1.0f + __expf(-bp));
        float x0 = beta * xr0 + (1.0f - beta) * out0;
        float x1 = beta * xr1 + (1.0f - beta) * out1;
        x0 = (x0 >= 0.f) ? x0 : 0.01f * x0;
        x1 = (x1 >= 0.f) ? x1 : 0.01f * x1;
        u16 h, l16;
        size_t base = (size_t)n * 256 + coff;
        bsplit(x0, h, l16); XoH[base + lane] = h;      XoL[base + lane] = l16;
        bsplit(x1, h, l16); XoH[base + 64 + lane] = h; XoL[base + 64 + lane] = l16;
    }
}

// ---------------------------------------------------------------------------
extern "C" void kernel_launch(void* const* d_in, const int* in_sizes, int n_in,
                              void* d_out, int out_size, void* d_ws, size_t ws_size,
                              hipStream_t stream) {
    const float* x_in  = (const float*)d_in[0];
    const int*   eidx  = (const int*)d_in[1];
    const float* eatt  = (const float*)d_in[2];
    const float* Wq1 = (const float*)d_in[3];  const float* bq1 = (const float*)d_in[4];
    const float* Wk1 = (const float*)d_in[5];  const float* bk1 = (const float*)d_in[6];
    const float* Wv1 = (const float*)d_in[7];  const float* bv1 = (const float*)d_in[8];
    const float* We1 = (const float*)d_in[9];
    const float* Wskip1 = (const float*)d_in[10]; const float* bskip1 = (const float*)d_in[11];
    const float* Wbeta1 = (const float*)d_in[12];
    const float* Wq2 = (const float*)d_in[13]; const float* bq2 = (const float*)d_in[14];
    const float* Wk2 = (const float*)d_in[15]; const float* bk2 = (const float*)d_in[16];
    const float* Wv2 = (const float*)d_in[17]; const float* bv2 = (const float*)d_in[18];
    const float* We2 = (const float*)d_in[19];
    const float* Wskip2 = (const float*)d_in[20]; const float* bskip2 = (const float*)d_in[21];
    const float* Wbeta2 = (const float*)d_in[22];
    const float* Wm  = (const float*)d_in[23]; const float* bm  = (const float*)d_in[24];

    const int N = in_sizes[0] / 256;
    const int E = in_sizes[1] / 2;
    const int* srcp = eidx;
    const int* dstp = eidx + E;

    char* p = (char*)d_ws;
    auto alloc = [&](size_t bytes) -> void* {
        void* r = (void*)p;
        p += (bytes + 255) & ~(size_t)255;
        return r;
    };
    int*   row_ptr  = (int*)alloc((size_t)(N + 1) * 4);
    int*   fillb    = (int*)alloc((size_t)(N + 1) * 4);
    int*   partials = (int*)alloc(256 * 4);
    int2*  esi      = (int2*)alloc((size_t)E * 8);
    float* QKVS = (float*)alloc((size_t)N * 576 * 4);   // Q|K|V|Skip|QE (K/V repacked)
    u16*   XpH  = (u16*)alloc((size_t)N * 256 * 2);     // input / xcat hi plane
    u16*   XpL  = (u16*)alloc((size_t)N * 256 * 2);
    float* WeT1 = (float*)alloc((size_t)64 * 128 * 4);
    float* WeT2 = (float*)alloc((size_t)64 * 128 * 4);
    u16*   Wc1H = (u16*)alloc((size_t)576 * 256 * 2);
    u16*   Wc1L = (u16*)alloc((size_t)576 * 256 * 2);
    u16*   Wc2H = (u16*)alloc((size_t)576 * 128 * 2);
    u16*   Wc2L = (u16*)alloc((size_t)576 * 128 * 2);
    float* bcat1 = (float*)alloc(576 * 4);
    float* bcat2 = (float*)alloc(576 * 4);
    u16*   WmH  = (u16*)alloc((size_t)64 * 256 * 2);
    u16*   WmL  = (u16*)alloc((size_t)64 * 256 * 2);

    // ---- CSR build ----
    hipMemsetAsync(fillb, 0, (size_t)(N + 1) * 4, stream);
    count_deg<<<(E + 255) / 256, 256, 0, stream>>>(dstp, fillb, E);
    int nScanBlocks = (N + 1 + 1023) / 1024;
    scan_a<<<nScanBlocks, 1024, 0, stream>>>(fillb, row_ptr, partials, N);
    scan_b<<<1, 1, 0, stream>>>(partials, nScanBlocks);
    scan_c<<<nScanBlocks, 1024, 0, stream>>>(row_ptr, partials, fillb, N);
    fill_edges<<<(E + 255) / 256, 256, 0, stream>>>(srcp, dstp, fillb, esi, E);

    // ---- weight prep (single kernel) ----
    prep_weights<<<1155, 256, 0, stream>>>(
        Wq1, Wk1, Wv1, Wskip1, We1, bq1, bk1, bv1, bskip1,
        Wq2, Wk2, Wv2, Wskip2, We2, bq2, bk2, bv2, bskip2, Wm,
        Wc1H, Wc1L, Wc2H, Wc2L, bcat1, bcat2, WeT1, WeT2, WmH, WmL);

    // ---- input planes ----
    split_planes<<<(N * 256 / 4 + 255) / 256, 256, 0, stream>>>(x_in, XpH, XpL, N * 256);

    dim3 blk(256);
    int gmx = (N + BM - 1) / BM;  // 391

    // ---- layer 1 ----
    gemm_mfma<<<dim3(gmx, 9), blk, 0, stream>>>(XpH, XpL, 256, Wc1H, Wc1L, bcat1,
                                                QKVS, 576, N, 256);
    pack_attn<<<2048, blk, 0, stream>>>(QKVS, N);
    attn4<<<1024, blk, 0, stream>>>(row_ptr, esi, QKVS, eatt, WeT1, Wbeta1,
                                    XpH, XpL, 0, N);

    // ---- layer 2 (input = planes cols 0..127) ----
    gemm_mfma<<<dim3(gmx, 9), blk, 0, stream>>>(XpH, XpL, 256, Wc2H, Wc2L, bcat2,
                                                QKVS, 576, N, 128);
    pack_attn<<<2048, blk, 0, stream>>>(QKVS, N);
    attn4<<<1024, blk, 0, stream>>>(row_ptr, esi, QKVS, eatt, WeT2, Wbeta2,
                                    XpH, XpL, 128, N);

    // ---- output MLP ----
    gemm_mfma<<<dim3(gmx, 1), blk, 0, stream>>>(XpH, XpL, 256, WmH, WmL, bm,
                                                (float*)d_out, 64, N, 256);
}

// Round 8
// 1057.234 us; speedup vs baseline: 1.4889x; 1.4889x over previous
//
#include <hip/hip_runtime.h>
#include <hip/hip_bf16.h>
#include <math.h>

// N=50000, E=800000, D_IN=256, D_E=64, H1=H2=128, N_OUT=64
typedef unsigned short u16;
typedef unsigned int u32;
typedef __attribute__((ext_vector_type(8))) short bf16x8;
typedef __attribute__((ext_vector_type(4))) float f32x4;

__device__ inline u16 f2bf(float x) {
    unsigned u = __float_as_uint(x);
    unsigned r = u + 0x7fff + ((u >> 16) & 1);
    return (u16)(r >> 16);
}
__device__ inline float bf2f(u16 h) { return __uint_as_float(((unsigned)h) << 16); }
__device__ inline void bsplit(float x, u16& h, u16& l) {
    h = f2bf(x);
    float r = x - bf2f(h);
    l = f2bf(r);
}

// ---------------------------------------------------------------------------
// CSR build
// ---------------------------------------------------------------------------
__global__ void count_deg(const int* __restrict__ dst, int* __restrict__ cnt, int E) {
    int e = blockIdx.x * blockDim.x + threadIdx.x;
    if (e < E) atomicAdd(&cnt[dst[e]], 1);
}

__global__ __launch_bounds__(1024) void scan_a(const int* __restrict__ cnt,
                                               int* __restrict__ out,
                                               int* __restrict__ partials, int N) {
    __shared__ int sh[1024];
    int tid = threadIdx.x;
    int gid = blockIdx.x * 1024 + tid;
    int v = (gid < N) ? cnt[gid] : 0;
    sh[tid] = v;
    for (int off = 1; off < 1024; off <<= 1) {
        __syncthreads();
        int add = (tid >= off) ? sh[tid - off] : 0;
        __syncthreads();
        sh[tid] += add;
    }
    __syncthreads();
    if (gid <= N) out[gid] = sh[tid] - v;
    if (tid == 1023) partials[blockIdx.x] = sh[1023];
}

__global__ void scan_b(int* __restrict__ partials, int nb) {
    if (threadIdx.x == 0 && blockIdx.x == 0) {
        int run = 0;
        for (int i = 0; i < nb; ++i) { int t = partials[i]; partials[i] = run; run += t; }
    }
}

__global__ __launch_bounds__(1024) void scan_c(int* __restrict__ out,
                                               const int* __restrict__ partials,
                                               int* __restrict__ fillb, int N) {
    int gid = blockIdx.x * 1024 + threadIdx.x;
    if (gid <= N) {
        int v = out[gid] + partials[blockIdx.x];
        out[gid] = v;
        fillb[gid] = v;
    }
}

__global__ void fill_edges(const int* __restrict__ src, const int* __restrict__ dst,
                           int* __restrict__ fillb, int2* __restrict__ esi, int E) {
    int e = blockIdx.x * blockDim.x + threadIdx.x;
    if (e < E) {
        int d = dst[e];
        int slot = atomicAdd(&fillb[d], 1);
        esi[slot] = make_int2(src[e], e);
    }
}

// ---------------------------------------------------------------------------
// prep_weights: one kernel for all weight prep (as R7).
// ---------------------------------------------------------------------------
__global__ __launch_bounds__(256) void prep_weights(
    const float* __restrict__ Wq1, const float* __restrict__ Wk1,
    const float* __restrict__ Wv1, const float* __restrict__ Ws1,
    const float* __restrict__ We1,
    const float* __restrict__ bq1, const float* __restrict__ bk1,
    const float* __restrict__ bv1, const float* __restrict__ bs1,
    const float* __restrict__ Wq2, const float* __restrict__ Wk2,
    const float* __restrict__ Wv2, const float* __restrict__ Ws2,
    const float* __restrict__ We2,
    const float* __restrict__ bq2, const float* __restrict__ bk2,
    const float* __restrict__ bv2, const float* __restrict__ bs2,
    const float* __restrict__ Wm,
    u16* __restrict__ Wc1H, u16* __restrict__ Wc1L,
    u16* __restrict__ Wc2H, u16* __restrict__ Wc2L,
    float* __restrict__ bcat1, float* __restrict__ bcat2,
    float* __restrict__ WeT1, float* __restrict__ WeT2,
    u16* __restrict__ WmH, u16* __restrict__ WmL) {
    int b = blockIdx.x;
    int t = threadIdx.x;
    if (b < 1152) {
        int L = b / 576;
        int r = b - L * 576;
        int K = L ? 128 : 256;
        const float* Wq = L ? Wq2 : Wq1;
        const float* We = L ? We2 : We1;
        u16* WH = L ? Wc2H : Wc1H;
        u16* WL = L ? Wc2L : Wc1L;
        float* bcat = L ? bcat2 : bcat1;
        float val = 0.f;
        bool have = t < K;
        if (r < 512) {
            int sub = r >> 7, rr = r & 127;
            const float* Wsrc = L ? (sub == 0 ? Wq2 : sub == 1 ? Wk2 : sub == 2 ? Wv2 : Ws2)
                                  : (sub == 0 ? Wq1 : sub == 1 ? Wk1 : sub == 2 ? Wv1 : Ws1);
            if (have) val = Wsrc[(size_t)rr * K + t];
            if (t == 0) {
                const float* bsrc = L ? (sub == 0 ? bq2 : sub == 1 ? bk2 : sub == 2 ? bv2 : bs2)
                                      : (sub == 0 ? bq1 : sub == 1 ? bk1 : sub == 2 ? bv1 : bs1);
                bcat[r] = bsrc[rr];
            }
        } else {
            int o = r - 512;
            if (have) {
                float s = 0.f;
                for (int h = 0; h < 128; ++h)
                    s = fmaf(We[h * 64 + o], Wq[(size_t)h * K + t], s);
                val = s;
            }
            if (t == 0) {
                const float* bq = L ? bq2 : bq1;
                float sb = 0.f;
                for (int h = 0; h < 128; ++h) sb = fmaf(We[h * 64 + o], bq[h], sb);
                bcat[r] = sb;
            }
        }
        if (have) {
            u16 h, l;
            bsplit(val, h, l);
            WH[(size_t)r * K + t] = h;
            WL[(size_t)r * K + t] = l;
        }
    } else if (b == 1152 || b == 1153) {
        const float* We = (b == 1152) ? We1 : We2;
        float* WeT = (b == 1152) ? WeT1 : WeT2;
        for (int i = t; i < 128 * 64; i += 256)
            WeT[(i & 63) * 128 + (i >> 6)] = We[i];
    } else {
        for (int i = t; i < 64 * 256; i += 256) {
            u16 h, l;
            bsplit(Wm[i], h, l);
            WmH[i] = h;
            WmL[i] = l;
        }
    }
}

// ---------------------------------------------------------------------------
// split fp32 array into bf16 hi/lo planes
// ---------------------------------------------------------------------------
__global__ void split_planes(const float* __restrict__ src, u16* __restrict__ hi,
                             u16* __restrict__ lo, int n4) {
    int i = (blockIdx.x * blockDim.x + threadIdx.x) * 4;
    if (i < n4) {
        float4 v = *reinterpret_cast<const float4*>(&src[i]);
        u16 h0, h1, h2, h3, l0, l1, l2, l3;
        bsplit(v.x, h0, l0); bsplit(v.y, h1, l1);
        bsplit(v.z, h2, l2); bsplit(v.w, h3, l3);
        *reinterpret_cast<ushort4*>(&hi[i]) = make_ushort4(h0, h1, h2, h3);
        *reinterpret_cast<ushort4*>(&lo[i]) = make_ushort4(l0, l1, l2, l3);
    }
}

// ---------------------------------------------------------------------------
// Split-bf16 MFMA GEMM: Out[n][o] = bias[o] + sum_k X[n][k]*W[o][k]
// ---------------------------------------------------------------------------
#define BM 128
#define BO 64
#define BKX 64
#define LSTR 72
__global__ __launch_bounds__(256) void gemm_mfma(
    const u16* __restrict__ XH, const u16* __restrict__ XL, int ldx,
    const u16* __restrict__ WH, const u16* __restrict__ WL,
    const float* __restrict__ bias, float* __restrict__ Out, int ldo,
    int Nrows, int K) {
    __shared__ __align__(16) u16 XsH[BM * LSTR];
    __shared__ __align__(16) u16 XsL[BM * LSTR];
    __shared__ __align__(16) u16 WsH[BO * LSTR];
    __shared__ __align__(16) u16 WsL[BO * LSTR];
    int n0 = blockIdx.x * BM, o0 = blockIdx.y * BO;
    int t = threadIdx.x, wid = t >> 6, lane = t & 63;
    int xr = t >> 1, xk = (t & 1) * 32;
    int wr = t >> 2, wk = (t & 3) * 16;
    bool xok = (n0 + xr) < Nrows;
    const u16* xh = XH + (size_t)(n0 + xr) * ldx + xk;
    const u16* xl = XL + (size_t)(n0 + xr) * ldx + xk;
    const u16* wh = WH + (size_t)(o0 + wr) * K + wk;
    const u16* wl = WL + (size_t)(o0 + wr) * K + wk;
    f32x4 acc[2][4] = {};
    for (int k0 = 0; k0 < K; k0 += BKX) {
#pragma unroll
        for (int j = 0; j < 4; ++j) {
            bf16x8 vh = {0, 0, 0, 0, 0, 0, 0, 0};
            bf16x8 vl = {0, 0, 0, 0, 0, 0, 0, 0};
            if (xok) {
                vh = *reinterpret_cast<const bf16x8*>(xh + k0 + 8 * j);
                vl = *reinterpret_cast<const bf16x8*>(xl + k0 + 8 * j);
            }
            *reinterpret_cast<bf16x8*>(&XsH[xr * LSTR + xk + 8 * j]) = vh;
            *reinterpret_cast<bf16x8*>(&XsL[xr * LSTR + xk + 8 * j]) = vl;
        }
#pragma unroll
        for (int j = 0; j < 2; ++j) {
            *reinterpret_cast<bf16x8*>(&WsH[wr * LSTR + wk + 8 * j]) =
                *reinterpret_cast<const bf16x8*>(wh + k0 + 8 * j);
            *reinterpret_cast<bf16x8*>(&WsL[wr * LSTR + wk + 8 * j]) =
                *reinterpret_cast<const bf16x8*>(wl + k0 + 8 * j);
        }
        __syncthreads();
#pragma unroll
        for (int kc = 0; kc < 2; ++kc) {
            int kf = kc * 32 + (lane >> 4) * 8;
            int ar = wid * 32 + (lane & 15);
            bf16x8 aH0 = *reinterpret_cast<const bf16x8*>(&XsH[ar * LSTR + kf]);
            bf16x8 aH1 = *reinterpret_cast<const bf16x8*>(&XsH[(ar + 16) * LSTR + kf]);
            bf16x8 aL0 = *reinterpret_cast<const bf16x8*>(&XsL[ar * LSTR + kf]);
            bf16x8 aL1 = *reinterpret_cast<const bf16x8*>(&XsL[(ar + 16) * LSTR + kf]);
#pragma unroll
            for (int c = 0; c < 4; ++c) {
                int br = c * 16 + (lane & 15);
                bf16x8 bH = *reinterpret_cast<const bf16x8*>(&WsH[br * LSTR + kf]);
                bf16x8 bL = *reinterpret_cast<const bf16x8*>(&WsL[br * LSTR + kf]);
                acc[0][c] = __builtin_amdgcn_mfma_f32_16x16x32_bf16(aH0, bH, acc[0][c], 0, 0, 0);
                acc[1][c] = __builtin_amdgcn_mfma_f32_16x16x32_bf16(aH1, bH, acc[1][c], 0, 0, 0);
                acc[0][c] = __builtin_amdgcn_mfma_f32_16x16x32_bf16(aH0, bL, acc[0][c], 0, 0, 0);
                acc[1][c] = __builtin_amdgcn_mfma_f32_16x16x32_bf16(aH1, bL, acc[1][c], 0, 0, 0);
                acc[0][c] = __builtin_amdgcn_mfma_f32_16x16x32_bf16(aL0, bH, acc[0][c], 0, 0, 0);
                acc[1][c] = __builtin_amdgcn_mfma_f32_16x16x32_bf16(aL1, bH, acc[1][c], 0, 0, 0);
            }
        }
        __syncthreads();
    }
#pragma unroll
    for (int c = 0; c < 4; ++c) {
        int col = o0 + c * 16 + (lane & 15);
        float bb = bias ? bias[col] : 0.f;
#pragma unroll
        for (int r = 0; r < 2; ++r) {
            int rb = n0 + wid * 32 + r * 16 + (lane >> 4) * 4;
#pragma unroll
            for (int q = 0; q < 4; ++q) {
                int row = rb + q;
                if (row < Nrows) Out[(size_t)row * ldo + col] = acc[r][c][q] + bb;
            }
        }
    }
}

// ---------------------------------------------------------------------------
// pack_attn: in-place repack of QKVS rows (K -> float2 pairs, V -> bf16 u32).
// ---------------------------------------------------------------------------
__global__ __launch_bounds__(256) void pack_attn(float* __restrict__ QKVS, int Nn) {
    int gwid = (blockIdx.x * blockDim.x + threadIdx.x) >> 6;
    int lane = threadIdx.x & 63;
    int nw = (gridDim.x * blockDim.x) >> 6;
    for (int n = gwid; n < Nn; n += nw) {
        float* row = QKVS + (size_t)n * 576;
        float k0 = row[128 + lane], k1 = row[192 + lane];
        float v0 = row[256 + lane], v1 = row[320 + lane];
        u32 vp = ((u32)f2bf(v1) << 16) | (u32)f2bf(v0);
        *reinterpret_cast<float2*>(&row[128 + 2 * lane]) = make_float2(k0, k1);
        reinterpret_cast<u32*>(row)[256 + lane] = vp;
    }
}

// ---------------------------------------------------------------------------
// attn5: wave per node, 8-edge batches, NO LDS, NO epilogue (occupancy-first).
// Packed K (float2) + packed V (bf16 u32) + fp32 Ae. exp2-domain softmax.
// Writes Acc[n][192] = av0|av1|aa (normalized).
// ---------------------------------------------------------------------------
#define AB5 8
__global__ __launch_bounds__(256) void attn5(
    const int* __restrict__ row_ptr, const int2* __restrict__ esi,
    const float* __restrict__ QKVS, const float* __restrict__ Ae,
    float* __restrict__ Acc, int Nn) {
    int t = threadIdx.x;
    int wid = t >> 6, lane = t & 63;
    const float RS2 = 0.088388347648318447f * 1.4426950408889634f; // 1/sqrt(128)*log2e
    for (int n = blockIdx.x * 4 + wid; n < Nn; n += gridDim.x * 4) {
        int r0 = row_ptr[n], r1 = row_ptr[n + 1];
        const float* qrow = QKVS + (size_t)n * 576;
        float q0  = qrow[lane];
        float q1  = qrow[64 + lane];
        float qe0 = qrow[512 + lane];
        float m = -1e30f, l = 0.f, av0 = 0.f, av1 = 0.f, aa = 0.f;
        for (int p = r0; p < r1; p += AB5) {
            int2 se[AB5];
#pragma unroll
            for (int i = 0; i < AB5; ++i) {
                int pp = (p + i < r1) ? p + i : r1 - 1;
                se[i] = esi[pp];
            }
            float2 kp[AB5];
            u32 vu[AB5];
            float af[AB5];
#pragma unroll
            for (int i = 0; i < AB5; ++i)
                kp[i] = *reinterpret_cast<const float2*>(
                    &QKVS[(size_t)se[i].x * 576 + 128 + 2 * lane]);
#pragma unroll
            for (int i = 0; i < AB5; ++i)
                vu[i] = reinterpret_cast<const u32*>(
                    QKVS + (size_t)se[i].x * 576)[256 + lane];
#pragma unroll
            for (int i = 0; i < AB5; ++i) af[i] = Ae[(size_t)se[i].y * 64 + lane];
            float d[AB5];
#pragma unroll
            for (int i = 0; i < AB5; ++i)
                d[i] = fmaf(q0, kp[i].x, fmaf(q1, kp[i].y, qe0 * af[i]));
#pragma unroll
            for (int off = 32; off; off >>= 1) {
#pragma unroll
                for (int i = 0; i < AB5; ++i) d[i] += __shfl_xor(d[i], off, 64);
            }
            float sc[AB5];
#pragma unroll
            for (int i = 0; i < AB5; ++i) sc[i] = (p + i < r1) ? d[i] * RS2 : -1e30f;
            float bm = sc[0];
#pragma unroll
            for (int i = 1; i < AB5; ++i) bm = fmaxf(bm, sc[i]);
            float mn = fmaxf(m, bm);
            float scale = exp2f(m - mn);
            float w[AB5];
#pragma unroll
            for (int i = 0; i < AB5; ++i) w[i] = exp2f(sc[i] - mn);
            float ws = ((w[0] + w[1]) + (w[2] + w[3])) + ((w[4] + w[5]) + (w[6] + w[7]));
            l = fmaf(l, scale, ws);
            float s_aa = 0.f, s0 = 0.f, s1 = 0.f;
#pragma unroll
            for (int i = 0; i < AB5; ++i) {
                float v0 = __uint_as_float(vu[i] << 16);
                float v1 = __uint_as_float(vu[i] & 0xffff0000u);
                s_aa = fmaf(w[i], af[i], s_aa);
                s0   = fmaf(w[i], v0, s0);
                s1   = fmaf(w[i], v1, s1);
            }
            aa  = fmaf(aa,  scale, s_aa);
            av0 = fmaf(av0, scale, s0);
            av1 = fmaf(av1, scale, s1);
            m = mn;
        }
        float inv = 1.0f / (l + 1e-16f);
        float* arow = Acc + (size_t)n * 192;
        arow[lane]       = av0 * inv;
        arow[64 + lane]  = av1 * inv;
        arow[128 + lane] = aa * inv;
    }
}

// ---------------------------------------------------------------------------
// epilogue: out = av + We*aa ; beta gate ; leaky relu ; write hi/lo planes
// ---------------------------------------------------------------------------
__global__ __launch_bounds__(256) void epilogue_k(
    const float* __restrict__ Acc, const float* __restrict__ QKVS,
    const float* __restrict__ WeT, const float* __restrict__ Wbeta,
    u16* __restrict__ XoH, u16* __restrict__ XoL, int coff, int Nn) {
    __shared__ float WeS[64 * 128];
    __shared__ float wbA[128], wbB[128];
    int t = threadIdx.x;
    for (int i = t; i < 64 * 128; i += 256) WeS[i] = WeT[i];
    if (t < 128) {
        float w3 = Wbeta[256 + t];
        wbA[t] = Wbeta[t] + w3;
        wbB[t] = Wbeta[128 + t] - w3;
    }
    __syncthreads();
    int wid = t >> 6, lane = t & 63;
    for (int n = blockIdx.x * 4 + wid; n < Nn; n += gridDim.x * 4) {
        const float* ar = Acc + (size_t)n * 192;
        float out0 = ar[lane], out1 = ar[64 + lane], aa = ar[128 + lane];
#pragma unroll
        for (int j = 0; j < 64; ++j) {
            float aj = __shfl(aa, j, 64);
            out0 = fmaf(aj, WeS[j * 128 + lane], out0);
            out1 = fmaf(aj, WeS[j * 128 + 64 + lane], out1);
        }
        const float* qrow = QKVS + (size_t)n * 576;
        float xr0 = qrow[384 + lane], xr1 = qrow[448 + lane];
        float bp = wbA[lane] * out0 + wbA[64 + lane] * out1 +
                   wbB[lane] * xr0  + wbB[64 + lane] * xr1;
#pragma unroll
        for (int off = 32; off; off >>= 1) bp += __shfl_xor(bp, off, 64);
        float beta = 1.0f / (1.0f + __expf(-bp));
        float x0 = beta * xr0 + (1.0f - beta) * out0;
        float x1 = beta * xr1 + (1.0f - beta) * out1;
        x0 = (x0 >= 0.f) ? x0 : 0.01f * x0;
        x1 = (x1 >= 0.f) ? x1 : 0.01f * x1;
        u16 h, l16;
        size_t base = (size_t)n * 256 + coff;
        bsplit(x0, h, l16); XoH[base + lane] = h;      XoL[base + lane] = l16;
        bsplit(x1, h, l16); XoH[base + 64 + lane] = h; XoL[base + 64 + lane] = l16;
    }
}

// ---------------------------------------------------------------------------
extern "C" void kernel_launch(void* const* d_in, const int* in_sizes, int n_in,
                              void* d_out, int out_size, void* d_ws, size_t ws_size,
                              hipStream_t stream) {
    const float* x_in  = (const float*)d_in[0];
    const int*   eidx  = (const int*)d_in[1];
    const float* eatt  = (const float*)d_in[2];
    const float* Wq1 = (const float*)d_in[3];  const float* bq1 = (const float*)d_in[4];
    const float* Wk1 = (const float*)d_in[5];  const float* bk1 = (const float*)d_in[6];
    const float* Wv1 = (const float*)d_in[7];  const float* bv1 = (const float*)d_in[8];
    const float* We1 = (const float*)d_in[9];
    const float* Wskip1 = (const float*)d_in[10]; const float* bskip1 = (const float*)d_in[11];
    const float* Wbeta1 = (const float*)d_in[12];
    const float* Wq2 = (const float*)d_in[13]; const float* bq2 = (const float*)d_in[14];
    const float* Wk2 = (const float*)d_in[15]; const float* bk2 = (const float*)d_in[16];
    const float* Wv2 = (const float*)d_in[17]; const float* bv2 = (const float*)d_in[18];
    const float* We2 = (const float*)d_in[19];
    const float* Wskip2 = (const float*)d_in[20]; const float* bskip2 = (const float*)d_in[21];
    const float* Wbeta2 = (const float*)d_in[22];
    const float* Wm  = (const float*)d_in[23]; const float* bm  = (const float*)d_in[24];

    const int N = in_sizes[0] / 256;
    const int E = in_sizes[1] / 2;
    const int* srcp = eidx;
    const int* dstp = eidx + E;

    char* p = (char*)d_ws;
    auto alloc = [&](size_t bytes) -> void* {
        void* r = (void*)p;
        p += (bytes + 255) & ~(size_t)255;
        return r;
    };
    int*   row_ptr  = (int*)alloc((size_t)(N + 1) * 4);
    int*   fillb    = (int*)alloc((size_t)(N + 1) * 4);
    int*   partials = (int*)alloc(256 * 4);
    int2*  esi      = (int2*)alloc((size_t)E * 8);
    float* QKVS = (float*)alloc((size_t)N * 576 * 4);   // Q|K|V|Skip|QE (K/V repacked)
    float* Accb = (float*)alloc((size_t)N * 192 * 4);
    u16*   XpH  = (u16*)alloc((size_t)N * 256 * 2);     // input / xcat hi plane
    u16*   XpL  = (u16*)alloc((size_t)N * 256 * 2);
    float* WeT1 = (float*)alloc((size_t)64 * 128 * 4);
    float* WeT2 = (float*)alloc((size_t)64 * 128 * 4);
    u16*   Wc1H = (u16*)alloc((size_t)576 * 256 * 2);
    u16*   Wc1L = (u16*)alloc((size_t)576 * 256 * 2);
    u16*   Wc2H = (u16*)alloc((size_t)576 * 128 * 2);
    u16*   Wc2L = (u16*)alloc((size_t)576 * 128 * 2);
    float* bcat1 = (float*)alloc(576 * 4);
    float* bcat2 = (float*)alloc(576 * 4);
    u16*   WmH  = (u16*)alloc((size_t)64 * 256 * 2);
    u16*   WmL  = (u16*)alloc((size_t)64 * 256 * 2);

    // ---- CSR build ----
    hipMemsetAsync(fillb, 0, (size_t)(N + 1) * 4, stream);
    count_deg<<<(E + 255) / 256, 256, 0, stream>>>(dstp, fillb, E);
    int nScanBlocks = (N + 1 + 1023) / 1024;
    scan_a<<<nScanBlocks, 1024, 0, stream>>>(fillb, row_ptr, partials, N);
    scan_b<<<1, 1, 0, stream>>>(partials, nScanBlocks);
    scan_c<<<nScanBlocks, 1024, 0, stream>>>(row_ptr, partials, fillb, N);
    fill_edges<<<(E + 255) / 256, 256, 0, stream>>>(srcp, dstp, fillb, esi, E);

    // ---- weight prep (single kernel) ----
    prep_weights<<<1155, 256, 0, stream>>>(
        Wq1, Wk1, Wv1, Wskip1, We1, bq1, bk1, bv1, bskip1,
        Wq2, Wk2, Wv2, Wskip2, We2, bq2, bk2, bv2, bskip2, Wm,
        Wc1H, Wc1L, Wc2H, Wc2L, bcat1, bcat2, WeT1, WeT2, WmH, WmL);

    // ---- input planes ----
    split_planes<<<(N * 256 / 4 + 255) / 256, 256, 0, stream>>>(x_in, XpH, XpL, N * 256);

    dim3 blk(256);
    int gmx = (N + BM - 1) / BM;  // 391

    // ---- layer 1 ----
    gemm_mfma<<<dim3(gmx, 9), blk, 0, stream>>>(XpH, XpL, 256, Wc1H, Wc1L, bcat1,
                                                QKVS, 576, N, 256);
    pack_attn<<<2048, blk, 0, stream>>>(QKVS, N);
    attn5<<<2048, blk, 0, stream>>>(row_ptr, esi, QKVS, eatt, Accb, N);
    epilogue_k<<<1024, blk, 0, stream>>>(Accb, QKVS, WeT1, Wbeta1, XpH, XpL, 0, N);

    // ---- layer 2 (input = planes cols 0..127) ----
    gemm_mfma<<<dim3(gmx, 9), blk, 0, stream>>>(XpH, XpL, 256, Wc2H, Wc2L, bcat2,
                                                QKVS, 576, N, 128);
    pack_attn<<<2048, blk, 0, stream>>>(QKVS, N);
    attn5<<<2048, blk, 0, stream>>>(row_ptr, esi, QKVS, eatt, Accb, N);
    epilogue_k<<<1024, blk, 0, stream>>>(Accb, QKVS, WeT2, Wbeta2, XpH, XpL, 128, N);

    // ---- output MLP ----
    gemm_mfma<<<dim3(gmx, 1), blk, 0, stream>>>(XpH, XpL, 256, WmH, WmL, bm,
                                                (float*)d_out, 64, N, 256);
}